// Round 10
// baseline (221.772 us; speedup 1.0000x reference)
//
#include <hip/hip_runtime.h>

#define NROWS 32768
#define NBLK  2048   // 4 waves/block, 4 rows per wave
#define RPW   4

typedef _Float16 h2 __attribute__((ext_vector_type(2)));

#define H2C(a,b) {(_Float16)(a##f), (_Float16)(b##f)}

__device__ __forceinline__ float DOT2(unsigned w, h2 f, float acc) {
#if __has_builtin(__builtin_amdgcn_fdot2)
    return __builtin_amdgcn_fdot2(__builtin_bit_cast(h2, w), f, acc, false);
#else
    h2 v = __builtin_bit_cast(h2, w);
    return fmaf((float)v.y, (float)f.y, fmaf((float)v.x, (float)f.x, acc));
#endif
}

__device__ __forceinline__ unsigned PK(float lo, float hi) {
    return __builtin_bit_cast(unsigned, __builtin_amdgcn_cvt_pkrtz(lo, hi));
}

struct Win { uint4 q0, q1, q2; };

__device__ __forceinline__ Win read_win(const unsigned* __restrict__ b, int g) {
    Win w;
    w.q0 = *(const uint4*)(b + 4 * g);
    w.q1 = *(const uint4*)(b + 4 * g + 4);
    w.q2 = *(const uint4*)(b + 4 * g + 8);
    return w;
}

template<int M, bool STORE>
__device__ __forceinline__ float comp(const Win& Wn, unsigned* __restrict__ outb,
                                      int g, bool valid)
{
    constexpr h2 FA[8] = {
        H2C(0.05441584224308161, 0.3128715909144659),
        H2C(0.6756307362980128, 0.5853546836548691),
        H2C(-0.015829105256023893, -0.2840155429624281),
        H2C(0.00047248457399797254, 0.128747426620186),
        H2C(-0.01736930100202211, -0.04408825393106472),
        H2C(0.013981027917015516, 0.008746094047015655),
        H2C(-0.00487035299301066, -0.0003917403729959771),
        H2C(0.0006754494059985568, -0.00011747678400228192)
    };
    constexpr h2 FD[8] = {
        H2C(-0.00011747678400228192, -0.0006754494059985568),
        H2C(-0.0003917403729959771, 0.00487035299301066),
        H2C(0.008746094047015655, -0.013981027917015516),
        H2C(-0.04408825393106472, 0.01736930100202211),
        H2C(0.128747426620186, -0.00047248457399797254),
        H2C(-0.2840155429624281, 0.015829105256023893),
        H2C(0.5853546836548691, -0.6756307362980128),
        H2C(0.3128715909144659, -0.05441584224308161)
    };
    const unsigned w[12] = {Wn.q0.x,Wn.q0.y,Wn.q0.z,Wn.q0.w,
                            Wn.q1.x,Wn.q1.y,Wn.q1.z,Wn.q1.w,
                            Wn.q2.x,Wn.q2.y,Wn.q2.z,Wn.q2.w};

    float aj[4] = {0.f,0.f,0.f,0.f}, dj[4] = {0.f,0.f,0.f,0.f};
#pragma unroll
    for (int c = 0; c < 8; ++c) {
#pragma unroll
        for (int j = 0; j < 4; ++j) {
            if constexpr (STORE) aj[j] = DOT2(w[j+1+c], FA[c], aj[j]);
            dj[j] = DOT2(w[j+1+c], FD[c], dj[j]);
        }
    }
    const int i0 = 4 * g;
    float ds = 0.f;
    if (valid) {
        ds = dj[0] * dj[0];
        if (i0 + 1 < M) ds += dj[1] * dj[1];
        if (i0 + 2 < M) ds += dj[2] * dj[2];
        if (i0 + 3 < M) ds += dj[3] * dj[3];
    }
    if constexpr (STORE) {
        if (valid) {
            constexpr int q = (M - 1) / 2;
            if (i0 + 3 < M) {
                *(uint2*)(outb + 8 + 2 * g) = make_uint2(PK(aj[0], aj[1]), PK(aj[2], aj[3]));
            } else if (i0 + 3 == M) {
                *(uint2*)(outb + 8 + 2 * g) = make_uint2(PK(aj[0], aj[1]), PK(aj[2], aj[2]));
            }
            if (g <= 3) outb[7 - 2 * g] = PK(aj[1], aj[0]);
            if (g <= 2) outb[6 - 2 * g] = PK(aj[3], aj[2]);
            const int p0 = 2 * g, p1 = 2 * g + 1;
            if ((unsigned)(p0 - (q - 7)) <= 6u) outb[8 + 2 * q - p0] = PK(aj[1], aj[0]);
            if ((unsigned)(p1 - (q - 7)) <= 6u) outb[8 + 2 * q - p1] = PK(aj[3], aj[2]);
        }
    }
    return ds;
}

__device__ __forceinline__ float spectral_row(const float4* xc, int lane) {
    float s = 0.f;
#pragma unroll
    for (int c = 0; c < 4; ++c) {
        const float4 xv = xc[c];
        float n0 = __shfl_down(xv.x, 1, 64);
        float n1 = __shfl_down(xv.y, 1, 64);
        if (c < 3) {
            const float b0 = __shfl(xc[c + 1].x, 0, 64);
            const float b1 = __shfl(xc[c + 1].y, 0, 64);
            if (lane == 63) { n0 = b0; n1 = b1; }
        }
        const float sd0 = xv.x - 2.f * xv.y + xv.z;
        const float sd1 = xv.y - 2.f * xv.z + xv.w;
        s += sd0 * sd0 + sd1 * sd1;
        const float sd2 = xv.z - 2.f * xv.w + n0;
        const float sd3 = xv.w - 2.f * n0 + n1;
        if (c < 3 || lane < 63)
            s += sd2 * sd2 + sd3 * sd3;
    }
    return s;
}

// MODE 0: full (real result).  Probes (write to scratch only):
// MODE 1: no spectral.  MODE 2: no DWT levels (staging kept).
// MODE 3: loads+MSE only (no LDS).  MODE 4: no real loads (synthetic rows), full compute.
template<int MODE>
__global__ __launch_bounds__(256) void cl_kernel(
    const float* __restrict__ x, const float* __restrict__ y,
    float* __restrict__ outp)
{
    constexpr bool kSpec  = (MODE == 0 || MODE == 2 || MODE == 4);
    constexpr bool kDWT   = (MODE == 0 || MODE == 1 || MODE == 4);
    constexpr bool kStage = (MODE != 3);
    constexpr bool kLoads = (MODE != 4);

    __shared__ __align__(16) unsigned lds[4][956];
    __shared__ float wsum[4];

    const int tid  = threadIdx.x;
    const int wid  = tid >> 6;
    const int lane = tid & 63;
    unsigned* const W  = lds[wid];
    unsigned* const B0 = W;
    unsigned* const B1 = W + 528;
    unsigned* const B2 = W + 804;

    const int rbase = (blockIdx.x * 4 + wid) * RPW;
    const float4* xp = (const float4*)x + (size_t)rbase * 256;
    const float4* yp = (const float4*)y + (size_t)rbase * 256;

    float4 xc[4], yc[4];
    float4 seed = make_float4(0.f, 0.f, 0.f, 0.f);
    if constexpr (kLoads) {
#pragma unroll
        for (int c = 0; c < 4; ++c) {
            xc[c] = xp[c * 64 + lane];
            yc[c] = yp[c * 64 + lane];
        }
    } else {
        seed = xp[lane];   // one load per lane; rows synthesized from it
    }

    float s_mse = 0.f, s_spec = 0.f, s_d1 = 0.f, s_d2 = 0.f, s_d3 = 0.f;

#pragma unroll 1
    for (int k = 0; k < RPW; ++k) {
        if constexpr (!kLoads) {
#pragma unroll
            for (int c = 0; c < 4; ++c) {
                xc[c] = make_float4(seed.x + (float)(c + k), seed.y - (float)c,
                                    seed.z + 0.5f * (float)c, seed.w);
                yc[c] = make_float4(seed.y, seed.z * 0.5f, seed.w - 1.f, seed.x);
            }
        }
        // ---- staging + MSE
#pragma unroll
        for (int c = 0; c < 4; ++c) {
            const int u = c * 64 + lane;
            const float4 e = make_float4(xc[c].x - yc[c].x, xc[c].y - yc[c].y,
                                         xc[c].z - yc[c].z, xc[c].w - yc[c].w);
            s_mse += e.x * e.x + e.y * e.y + e.z * e.z + e.w * e.w;
            if constexpr (kStage) {
                *(uint2*)(B0 + 8 + 2 * u) = make_uint2(PK(e.x, e.y), PK(e.z, e.w));
                if (c == 0 && lane <= 3) {
                    B0[7 - 2 * lane] = PK(e.y, e.x);
                    if (lane <= 2) B0[6 - 2 * lane] = PK(e.w, e.z);
                }
                if (c == 3 && lane >= 60) {
                    if (lane >= 61) B0[1031 - 2 * u] = PK(e.y, e.x);
                    B0[1030 - 2 * u] = PK(e.w, e.z);
                }
            }
        }

        if constexpr (kSpec) s_spec += spectral_row(xc, lane);

        // prefetch next row (loads in flight across the level chain)
        if (kLoads && k + 1 < RPW) {
            const float4* ypn = yp + (size_t)(k + 1) * 256;
            const float4* xpn = xp + (size_t)(k + 1) * 256;
#pragma unroll
            for (int c = 0; c < 4; ++c) yc[c] = ypn[c * 64 + lane];
#pragma unroll
            for (int c = 0; c < 4; ++c) xc[c] = xpn[c * 64 + lane];
        }

        if constexpr (kDWT) {
            const Win w0 = read_win(B0, lane);
            const Win w1 = read_win(B0, lane + 64);
            s_d1 += comp<519, true>(w0, B1, lane, true);
            const int g2 = lane < 2 ? lane + 128 : 129;
            const Win w2 = read_win(B0, g2);
            s_d1 += comp<519, true>(w1, B1, lane + 64, true);
            s_d1 += comp<519, true>(w2, B1, g2, lane < 2);

            const Win v0 = read_win(B1, lane);
            const int h1 = lane < 3 ? lane + 64 : 66;
            const Win v1 = read_win(B1, h1);
            s_d2 += comp<267, true>(v0, B2, lane, true);
            s_d2 += comp<267, true>(v1, B2, h1, lane < 3);

            const int g3 = lane < 36 ? lane : 35;
            const Win u0 = read_win(B2, g3);
            s_d3 += comp<141, false>(u0, B2, g3, lane < 36);
        }
    }

    const float wm  = 1.0f / 33554432.0f;
    const float wsp = 1.0f / 33488896.0f;
    const float w1w = 1.0f / (3.0f * 17006592.0f);
    const float w2w = 1.0f / (3.0f * 8749056.0f);
    const float w3w = 1.0f / (3.0f * 4620288.0f);
    float local = wm * s_mse + wsp * s_spec + w1w * s_d1 + w2w * s_d2 + w3w * s_d3;

#pragma unroll
    for (int off = 32; off > 0; off >>= 1)
        local += __shfl_down(local, off, 64);
    if (lane == 0) wsum[wid] = local;
    __syncthreads();
    if (tid == 0) outp[blockIdx.x] = wsum[0] + wsum[1] + wsum[2] + wsum[3];
}

__global__ __launch_bounds__(256) void reduce_kernel(const float* __restrict__ partials,
                                                     int n, float* __restrict__ out)
{
    __shared__ double sm[256];
    double s = 0.0;
    for (int i = threadIdx.x; i < n; i += 256) s += (double)partials[i];
    sm[threadIdx.x] = s;
    __syncthreads();
    for (int off = 128; off > 0; off >>= 1) {
        if (threadIdx.x < off) sm[threadIdx.x] += sm[threadIdx.x + off];
        __syncthreads();
    }
    if (threadIdx.x == 0) out[0] = (float)sm[0];
}

extern "C" void kernel_launch(void* const* d_in, const int* in_sizes, int n_in,
                              void* d_out, int out_size, void* d_ws, size_t ws_size,
                              hipStream_t stream) {
    const float* x = (const float*)d_in[0];   // output
    const float* y = (const float*)d_in[1];   // target
    float* pw = (float*)d_ws;

    // real result
    cl_kernel<0><<<NBLK, 256, 0, stream>>>(x, y, pw);
    reduce_kernel<<<1, 256, 0, stream>>>(pw, NBLK, (float*)d_out);

    // ablation probes (diagnostic; write only to scratch beyond partials)
    if (ws_size >= (size_t)5 * NBLK * sizeof(float)) {
        cl_kernel<1><<<NBLK, 256, 0, stream>>>(x, y, pw + 1 * NBLK);
        cl_kernel<2><<<NBLK, 256, 0, stream>>>(x, y, pw + 2 * NBLK);
        cl_kernel<3><<<NBLK, 256, 0, stream>>>(x, y, pw + 3 * NBLK);
        cl_kernel<4><<<NBLK, 256, 0, stream>>>(x, y, pw + 4 * NBLK);
    }
}

// Round 11
// 64.673 us; speedup vs baseline: 3.4291x; 3.4291x over previous
//
#include <hip/hip_runtime.h>

#define NROWS 32768
#define NBLK  2048   // 4 waves/block, 4 rows per wave (pipelined)
#define RPW   4

typedef _Float16 h2 __attribute__((ext_vector_type(2)));

// db8 dec filters, pre-reversed (out[i] = sum_k in[2i+k-14]*F[k]), packed as f16 pairs
#define H2C(a,b) {(_Float16)(a##f), (_Float16)(b##f)}

__device__ __forceinline__ float DOT2(unsigned w, h2 f, float acc) {
#if __has_builtin(__builtin_amdgcn_fdot2)
    return __builtin_amdgcn_fdot2(__builtin_bit_cast(h2, w), f, acc, false);
#else
    h2 v = __builtin_bit_cast(h2, w);
    return fmaf((float)v.y, (float)f.y, fmaf((float)v.x, (float)f.x, acc));
#endif
}

__device__ __forceinline__ unsigned PK(float lo, float hi) {
    return __builtin_bit_cast(unsigned, __builtin_amdgcn_cvt_pkrtz(lo, hi));
}

__device__ __forceinline__ unsigned ROR16(unsigned v) { return (v >> 16) | (v << 16); }

__device__ __forceinline__ void wave_lgkm0() {
    asm volatile("s_waitcnt lgkmcnt(0)" ::: "memory");
}

// --- LDS chunk swizzle: 16B chunk c -> c ^ ((c>>3)&7). Bijective within each
// aligned 8-chunk block; spreads the stride-32B window reads across all banks.
__device__ __forceinline__ unsigned pc_chunk(unsigned c) { return c ^ ((c >> 3) & 7u); }
__device__ __forceinline__ unsigned swz32(unsigned i) {   // u32-index transform
    return (pc_chunk(i >> 2) << 2) | (i & 3u);
}
__device__ __forceinline__ uint4 ldc(const unsigned* __restrict__ b, unsigned c) {
    return ((const uint4*)b)[pc_chunk(c)];
}

// One DWT level, 8 outputs per lane. Buffer: pair p at u32 idx 8+p (front pads
// idx 1..7, tail mirror pads after data), all accesses chunk-swizzled.
// Lane g (< G=M/8): outputs 8g..8g+7 from u32 window [8g..8g+15] (4 uint4 reads).
// out(8g+j) = sum_c dot2(pair[8g+j-7+c], F[c]) = sum_c dot2(w[j+1+c], F[c]).
// Tail outputs 8G..M-1 computed by lane 0 (static windows from chunks 2G..2G+3).
template<int M, bool STORE>
__device__ __forceinline__ float level8(const unsigned* __restrict__ IB,
                                        unsigned* __restrict__ OB, int lane)
{
    constexpr h2 FA[8] = {
        H2C(0.05441584224308161, 0.3128715909144659),
        H2C(0.6756307362980128, 0.5853546836548691),
        H2C(-0.015829105256023893, -0.2840155429624281),
        H2C(0.00047248457399797254, 0.128747426620186),
        H2C(-0.01736930100202211, -0.04408825393106472),
        H2C(0.013981027917015516, 0.008746094047015655),
        H2C(-0.00487035299301066, -0.0003917403729959771),
        H2C(0.0006754494059985568, -0.00011747678400228192)
    };
    constexpr h2 FD[8] = {
        H2C(-0.00011747678400228192, -0.0006754494059985568),
        H2C(-0.0003917403729959771, 0.00487035299301066),
        H2C(0.008746094047015655, -0.013981027917015516),
        H2C(-0.04408825393106472, 0.01736930100202211),
        H2C(0.128747426620186, -0.00047248457399797254),
        H2C(-0.2840155429624281, 0.015829105256023893),
        H2C(0.5853546836548691, -0.6756307362980128),
        H2C(0.3128715909144659, -0.05441584224308161)
    };
    constexpr int G    = M / 8;        // full groups: 64 / 33 / 17
    constexpr int TAIL = M - 8 * G;    // 7 / 3 / 5
    constexpr int q    = (M - 1) / 2;  // last stored pair (dup .y)
    float ds = 0.f;

    if (lane < G) {
        const uint4 c0 = ldc(IB, 2*lane+0), c1 = ldc(IB, 2*lane+1),
                    c2 = ldc(IB, 2*lane+2), c3 = ldc(IB, 2*lane+3);
        const unsigned w[16] = {c0.x,c0.y,c0.z,c0.w, c1.x,c1.y,c1.z,c1.w,
                                c2.x,c2.y,c2.z,c2.w, c3.x,c3.y,c3.z,c3.w};
        float a[8] = {0,0,0,0,0,0,0,0}, d[8] = {0,0,0,0,0,0,0,0};
#pragma unroll
        for (int c = 0; c < 8; ++c) {
#pragma unroll
            for (int j = 0; j < 8; ++j) {
                if constexpr (STORE) a[j] = DOT2(w[j+1+c], FA[c], a[j]);
                d[j] = DOT2(w[j+1+c], FD[c], d[j]);
            }
        }
#pragma unroll
        for (int j = 0; j < 8; ++j) ds += d[j] * d[j];
        if constexpr (STORE) {
            unsigned P[4];
#pragma unroll
            for (int t = 0; t < 4; ++t) P[t] = PK(a[2*t], a[2*t+1]);
            ((uint4*)OB)[pc_chunk(2 + lane)] = make_uint4(P[0], P[1], P[2], P[3]);
#pragma unroll
            for (int t = 0; t < 4; ++t) {
                const int p = 4 * lane + t;
                if (p <= 6)                   OB[swz32(7 - p)]       = ROR16(P[t]); // front mirrors
                if (p >= q - 7 && p <= q - 1) OB[swz32(8 + 2*q - p)] = ROR16(P[t]); // tail mirrors
            }
        }
    }
    // tail: outputs 8G .. M-1, lane 0 only (windows static per t)
    if (lane == 0) {
        const uint4 c0 = ldc(IB, 2*G+0), c1 = ldc(IB, 2*G+1),
                    c2 = ldc(IB, 2*G+2), c3 = ldc(IB, 2*G+3);
        const unsigned w[16] = {c0.x,c0.y,c0.z,c0.w, c1.x,c1.y,c1.z,c1.w,
                                c2.x,c2.y,c2.z,c2.w, c3.x,c3.y,c3.z,c3.w};
        float a[8] = {0,0,0,0,0,0,0,0};
#pragma unroll
        for (int t = 0; t < TAIL; ++t) {
            float at = 0.f, dt = 0.f;
#pragma unroll
            for (int c = 0; c < 8; ++c) {
                if constexpr (STORE) at = DOT2(w[t+1+c], FA[c], at);
                dt = DOT2(w[t+1+c], FD[c], dt);
            }
            ds += dt * dt;
            a[t] = at;
        }
        if constexpr (STORE) {
            if constexpr (TAIL == 7) {       // L1: pairs 4G..4G+3 (last dups)
                const unsigned P0 = PK(a[0], a[1]), P1 = PK(a[2], a[3]),
                               P2 = PK(a[4], a[5]), P3 = PK(a[6], a[6]);
                ((uint4*)OB)[pc_chunk(2 + G)] = make_uint4(P0, P1, P2, P3);
                OB[swz32(8 + 2*q - (4*G + 0))] = ROR16(P0);
                OB[swz32(8 + 2*q - (4*G + 1))] = ROR16(P1);
                OB[swz32(8 + 2*q - (4*G + 2))] = ROR16(P2);
            } else {                          // L2: TAIL == 3, pairs 4G..4G+1
                const unsigned P0 = PK(a[0], a[1]), P1 = PK(a[2], a[2]);
                *(uint2*)(OB + swz32(8 + 4*G)) = make_uint2(P0, P1);
                OB[swz32(8 + 2*q - 4*G)] = ROR16(P0);
            }
        }
    }
    return ds;
}

// spectral for one row held in registers: sd_i = x[i]-2x[i+1]+x[i+2], i<=1021 (f32 exact)
__device__ __forceinline__ float spectral_row(const float4* xc, int lane) {
    float s = 0.f;
#pragma unroll
    for (int c = 0; c < 4; ++c) {
        const float4 xv = xc[c];
        float n0 = __shfl_down(xv.x, 1, 64);
        float n1 = __shfl_down(xv.y, 1, 64);
        if (c < 3) {
            const float b0 = __shfl(xc[c + 1].x, 0, 64);
            const float b1 = __shfl(xc[c + 1].y, 0, 64);
            if (lane == 63) { n0 = b0; n1 = b1; }
        }
        const float sd0 = xv.x - 2.f * xv.y + xv.z;
        const float sd1 = xv.y - 2.f * xv.z + xv.w;
        s += sd0 * sd0 + sd1 * sd1;
        const float sd2 = xv.z - 2.f * xv.w + n0;
        const float sd3 = xv.w - 2.f * n0 + n1;
        if (c < 3 || lane < 63)
            s += sd2 * sd2 + sd3 * sd3;
    }
    return s;
}

__global__ __launch_bounds__(256) void combined_loss_kernel(
    const float* __restrict__ x, const float* __restrict__ y,
    float* __restrict__ partials)
{
    // per-wave u32 pair buffers (swizzled): B0[528] B1[276] B2[160] = 964 u32
    __shared__ __align__(16) unsigned lds[4][964];
    __shared__ float wsum[4];

    const int tid  = threadIdx.x;
    const int wid  = tid >> 6;
    const int lane = tid & 63;
    unsigned* const W  = lds[wid];
    unsigned* const B0 = W;          // L=1024: 8 front + 512 data + 7 tail
    unsigned* const B1 = W + 528;    // M=519:  8 + 260 + mirrors (idx to 274)
    unsigned* const B2 = W + 804;    // M=267:  8 + 134 + mirrors (padded to 160 for swizzle)

    const int rbase = (blockIdx.x * 4 + wid) * RPW;
    const float4* xp = (const float4*)x + (size_t)rbase * 256;
    const float4* yp = (const float4*)y + (size_t)rbase * 256;

    float4 xc[4], yc[4];
#pragma unroll
    for (int c = 0; c < 4; ++c) {
        xc[c] = xp[c * 64 + lane];
        yc[c] = yp[c * 64 + lane];
    }

    float s_mse = 0.f, s_spec = 0.f, s_d1 = 0.f, s_d2 = 0.f, s_d3 = 0.f;

#pragma unroll 1
    for (int k = 0; k < RPW; ++k) {
        // ---- stage current row with fused mirror pads (swizzled writes)
#pragma unroll
        for (int c = 0; c < 4; ++c) {
            const int u = c * 64 + lane;
            const float4 e = make_float4(xc[c].x - yc[c].x, xc[c].y - yc[c].y,
                                         xc[c].z - yc[c].z, xc[c].w - yc[c].w);
            s_mse += e.x * e.x + e.y * e.y + e.z * e.z + e.w * e.w;
            *(uint2*)(B0 + swz32(8 + 2 * u)) = make_uint2(PK(e.x, e.y), PK(e.z, e.w));
            if (c == 0 && lane <= 3) {           // front pads (reflection of e[0..13])
                B0[swz32(7 - 2 * lane)] = PK(e.y, e.x);
                if (lane <= 2) B0[swz32(6 - 2 * lane)] = PK(e.w, e.z);
            }
            if (c == 3 && lane >= 60) {          // tail pads (reflection of e[1009..1023])
                if (lane >= 61) B0[swz32(1031 - 2 * u)] = PK(e.y, e.x);
                B0[swz32(1030 - 2 * u)] = PK(e.w, e.z);
            }
        }
        s_spec += spectral_row(xc, lane);

        // prefetch next row; loads stay in flight across all three levels
        if (k + 1 < RPW) {
            const float4* ypn = yp + (size_t)(k + 1) * 256;
            const float4* xpn = xp + (size_t)(k + 1) * 256;
#pragma unroll
            for (int c = 0; c < 4; ++c) yc[c] = ypn[c * 64 + lane];
#pragma unroll
            for (int c = 0; c < 4; ++c) xc[c] = xpn[c * 64 + lane];
        }

        wave_lgkm0();
        s_d1 += level8<519, true>(B0, B1, lane);
        wave_lgkm0();
        s_d2 += level8<267, true>(B1, B2, lane);
        wave_lgkm0();
        s_d3 += level8<141, false>(B2, B2, lane);
    }

    const float wm  = 1.0f / 33554432.0f;             // 32*1024*1024
    const float wsp = 1.0f / 33488896.0f;             // 32*1024*1022
    const float w1w = 1.0f / (3.0f * 17006592.0f);    // 32768*519
    const float w2w = 1.0f / (3.0f * 8749056.0f);     // 32768*267
    const float w3w = 1.0f / (3.0f * 4620288.0f);     // 32768*141
    float local = wm * s_mse + wsp * s_spec + w1w * s_d1 + w2w * s_d2 + w3w * s_d3;

#pragma unroll
    for (int off = 32; off > 0; off >>= 1)
        local += __shfl_down(local, off, 64);
    if (lane == 0) wsum[wid] = local;
    __syncthreads();
    if (tid == 0) partials[blockIdx.x] = wsum[0] + wsum[1] + wsum[2] + wsum[3];
}

__global__ __launch_bounds__(256) void reduce_kernel(const float* __restrict__ partials,
                                                     int n, float* __restrict__ out)
{
    __shared__ double sm[256];
    double s = 0.0;
    for (int i = threadIdx.x; i < n; i += 256) s += (double)partials[i];
    sm[threadIdx.x] = s;
    __syncthreads();
    for (int off = 128; off > 0; off >>= 1) {
        if (threadIdx.x < off) sm[threadIdx.x] += sm[threadIdx.x + off];
        __syncthreads();
    }
    if (threadIdx.x == 0) out[0] = (float)sm[0];
}

extern "C" void kernel_launch(void* const* d_in, const int* in_sizes, int n_in,
                              void* d_out, int out_size, void* d_ws, size_t ws_size,
                              hipStream_t stream) {
    const float* x = (const float*)d_in[0];   // output
    const float* y = (const float*)d_in[1];   // target
    float* partials = (float*)d_ws;           // NBLK floats (8 KB)
    combined_loss_kernel<<<NBLK, 256, 0, stream>>>(x, y, partials);
    reduce_kernel<<<1, 256, 0, stream>>>(partials, NBLK, (float*)d_out);
}

// Round 12
// 54.146 us; speedup vs baseline: 4.0958x; 1.1944x over previous
//
#include <hip/hip_runtime.h>

#define NROWS 32768
#define NBLK  2048   // 4 waves/block, 4 rows per wave (pipelined)
#define RPW   4

typedef _Float16 h2 __attribute__((ext_vector_type(2)));

// db8 dec filters, pre-reversed (out[i] = sum_k in[2i+k-14]*F[k]), packed as f16 pairs
#define H2C(a,b) {(_Float16)(a##f), (_Float16)(b##f)}

__device__ __forceinline__ float DOT2(unsigned w, h2 f, float acc) {
#if __has_builtin(__builtin_amdgcn_fdot2)
    return __builtin_amdgcn_fdot2(__builtin_bit_cast(h2, w), f, acc, false);
#else
    h2 v = __builtin_bit_cast(h2, w);
    return fmaf((float)v.y, (float)f.y, fmaf((float)v.x, (float)f.x, acc));
#endif
}

__device__ __forceinline__ unsigned PK(float lo, float hi) {
    return __builtin_bit_cast(unsigned, __builtin_amdgcn_cvt_pkrtz(lo, hi));
}

// wave-internal LDS ordering only — NO barrier (waves are independent).
// Waits lgkm only: outstanding global loads (vmcnt) stay in flight.
__device__ __forceinline__ void wave_lgkm0() {
    asm volatile("s_waitcnt lgkmcnt(0)" ::: "memory");
}

// One group (4 outputs i=4g..4g+3) of one DWT level, f16-pair layout.
// Buffer: pair P[k] at u32 index 8+k; front pads P[-7..-1], tail pads per level.
// Window: w[m] = P[4g-8+m], m=0..11; out j uses w[j+1+c], c=0..7.
template<int M, bool STORE>
__device__ __forceinline__ float level_group(const unsigned* __restrict__ inb,
                                             unsigned* __restrict__ outb, int g)
{
    constexpr h2 FA[8] = {
        H2C(0.05441584224308161, 0.3128715909144659),
        H2C(0.6756307362980128, 0.5853546836548691),
        H2C(-0.015829105256023893, -0.2840155429624281),
        H2C(0.00047248457399797254, 0.128747426620186),
        H2C(-0.01736930100202211, -0.04408825393106472),
        H2C(0.013981027917015516, 0.008746094047015655),
        H2C(-0.00487035299301066, -0.0003917403729959771),
        H2C(0.0006754494059985568, -0.00011747678400228192)
    };
    constexpr h2 FD[8] = {
        H2C(-0.00011747678400228192, -0.0006754494059985568),
        H2C(-0.0003917403729959771, 0.00487035299301066),
        H2C(0.008746094047015655, -0.013981027917015516),
        H2C(-0.04408825393106472, 0.01736930100202211),
        H2C(0.128747426620186, -0.00047248457399797254),
        H2C(-0.2840155429624281, 0.015829105256023893),
        H2C(0.5853546836548691, -0.6756307362980128),
        H2C(0.3128715909144659, -0.05441584224308161)
    };
    const uint4 q0 = *(const uint4*)(inb + 4 * g);
    const uint4 q1 = *(const uint4*)(inb + 4 * g + 4);
    const uint4 q2 = *(const uint4*)(inb + 4 * g + 8);
    const unsigned w[12] = {q0.x,q0.y,q0.z,q0.w, q1.x,q1.y,q1.z,q1.w, q2.x,q2.y,q2.z,q2.w};

    float aj[4] = {0.f,0.f,0.f,0.f}, dj[4] = {0.f,0.f,0.f,0.f};
#pragma unroll
    for (int c = 0; c < 8; ++c) {
#pragma unroll
        for (int j = 0; j < 4; ++j) {
            if constexpr (STORE) aj[j] = DOT2(w[j+1+c], FA[c], aj[j]);  // DCE'd for L3
            dj[j] = DOT2(w[j+1+c], FD[c], dj[j]);
        }
    }
    const int i0 = 4 * g;
    float ds = dj[0] * dj[0];                 // i0 < M always
    if (i0 + 1 < M) ds += dj[1] * dj[1];
    if (i0 + 2 < M) ds += dj[2] * dj[2];
    if (i0 + 3 < M) ds += dj[3] * dj[3];
    if constexpr (STORE) {
        *(uint2*)(outb + 8 + 2 * g) = make_uint2(PK(aj[0], aj[1]), PK(aj[2], aj[3]));
    }
    return ds;
}

// fixups (wave-internal; caller brackets with wave_lgkm0). l must satisfy 0<=l<7 to act.
__device__ __forceinline__ unsigned ROR16(unsigned v) { return (v >> 16) | (v << 16); }
__device__ __forceinline__ void fix_front(unsigned* b, int l) {
    if ((unsigned)l < 7u) b[7 - l] = ROR16(b[8 + l]);
}
__device__ __forceinline__ void fix_tail_even(unsigned* b, int l, int HL) {
    if ((unsigned)l < 7u) b[8 + HL + l] = ROR16(b[8 + HL - 1 - l]);
}
__device__ __forceinline__ void fix_tail_odd(unsigned* b, int l, int q) {
    if ((unsigned)l < 7u) b[8 + q + 1 + l] = ROR16(b[8 + q - 1 - l]);
    if (l == 7) { unsigned v = b[8 + q]; b[8 + q] = (v & 0xffffu) | (v << 16); }
}

// spectral for one row held in registers: sd_i = x[i]-2x[i+1]+x[i+2], i<=1021 (f32 exact)
__device__ __forceinline__ float spectral_row(const float4* xc, int lane) {
    float s = 0.f;
#pragma unroll
    for (int c = 0; c < 4; ++c) {
        const float4 xv = xc[c];
        float n0 = __shfl_down(xv.x, 1, 64);
        float n1 = __shfl_down(xv.y, 1, 64);
        if (c < 3) {
            const float b0 = __shfl(xc[c + 1].x, 0, 64);
            const float b1 = __shfl(xc[c + 1].y, 0, 64);
            if (lane == 63) { n0 = b0; n1 = b1; }
        }
        const float sd0 = xv.x - 2.f * xv.y + xv.z;
        const float sd1 = xv.y - 2.f * xv.z + xv.w;
        s += sd0 * sd0 + sd1 * sd1;
        const float sd2 = xv.z - 2.f * xv.w + n0;
        const float sd3 = xv.w - 2.f * n0 + n1;
        if (c < 3 || lane < 63)
            s += sd2 * sd2 + sd3 * sd3;
    }
    return s;
}

__global__ __launch_bounds__(256) void combined_loss_kernel(
    const float* __restrict__ x, const float* __restrict__ y,
    float* __restrict__ partials)
{
    // per-wave u32 pair buffers: B0[528] B1[276] B2[152] = 956 u32 = 3824 B/wave
    __shared__ __align__(16) unsigned lds[4][956];
    __shared__ float wsum[4];

    const int tid  = threadIdx.x;
    const int wid  = tid >> 6;
    const int lane = tid & 63;
    unsigned* const W  = lds[wid];
    unsigned* const B0 = W;          // L=1024: 8 front + 512 data + 8 tail
    unsigned* const B1 = W + 528;    // M=519:  8 + 260 + 8
    unsigned* const B2 = W + 804;    // M=267:  8 + 134 + 10

    const int rbase = (blockIdx.x * 4 + wid) * RPW;
    const float4* xp = (const float4*)x + (size_t)rbase * 256;
    const float4* yp = (const float4*)y + (size_t)rbase * 256;

    float4 xc[4], yc[4];
#pragma unroll
    for (int c = 0; c < 4; ++c) {
        xc[c] = xp[c * 64 + lane];
        yc[c] = yp[c * 64 + lane];
    }

    float s_mse = 0.f, s_spec = 0.f, s_d1 = 0.f, s_d2 = 0.f, s_d3 = 0.f;

#pragma unroll 1
    for (int k = 0; k < RPW; ++k) {
        // stage current row (consumes yc; xc kept for spectral)
#pragma unroll
        for (int c = 0; c < 4; ++c) {
            const int u = c * 64 + lane;
            const float4 e = make_float4(xc[c].x - yc[c].x, xc[c].y - yc[c].y,
                                         xc[c].z - yc[c].z, xc[c].w - yc[c].w);
            s_mse += e.x * e.x + e.y * e.y + e.z * e.z + e.w * e.w;
            *(uint2*)(B0 + 8 + 2 * u) = make_uint2(PK(e.x, e.y), PK(e.z, e.w));
        }
        s_spec += spectral_row(xc, lane);

        // prefetch next row; loads stay in flight across all three levels (lgkm-only waits below)
        if (k + 1 < RPW) {
            const float4* xpn = xp + (size_t)(k + 1) * 256;
            const float4* ypn = yp + (size_t)(k + 1) * 256;
#pragma unroll
            for (int c = 0; c < 4; ++c) {
                xc[c] = xpn[c * 64 + lane];
                yc[c] = ypn[c * 64 + lane];
            }
        }

        wave_lgkm0();
        fix_front(B0, lane); fix_tail_even(B0, lane - 16, 512);
        wave_lgkm0();
        for (int g = lane; g < 130; g += 64) s_d1 += level_group<519, true>(B0, B1, g);
        wave_lgkm0();
        fix_front(B1, lane); fix_tail_odd(B1, lane - 16, 259);
        wave_lgkm0();
        for (int g = lane; g < 67; g += 64)  s_d2 += level_group<267, true>(B1, B2, g);
        wave_lgkm0();
        fix_front(B2, lane); fix_tail_odd(B2, lane - 16, 133);
        wave_lgkm0();
        if (lane < 36)                       s_d3 += level_group<141, false>(B2, B2, lane);
        // next iteration's B0 staging: same-wave DS ops execute in order -> no hazard
    }

    const float wm  = 1.0f / 33554432.0f;             // 32*1024*1024
    const float wsp = 1.0f / 33488896.0f;             // 32*1024*1022
    const float w1  = 1.0f / (3.0f * 17006592.0f);    // 32768*519
    const float w2  = 1.0f / (3.0f * 8749056.0f);     // 32768*267
    const float w3  = 1.0f / (3.0f * 4620288.0f);     // 32768*141
    float local = wm * s_mse + wsp * s_spec + w1 * s_d1 + w2 * s_d2 + w3 * s_d3;

#pragma unroll
    for (int off = 32; off > 0; off >>= 1)
        local += __shfl_down(local, off, 64);
    if (lane == 0) wsum[wid] = local;
    __syncthreads();
    if (tid == 0) partials[blockIdx.x] = wsum[0] + wsum[1] + wsum[2] + wsum[3];
}

__global__ __launch_bounds__(256) void reduce_kernel(const float* __restrict__ partials,
                                                     int n, float* __restrict__ out)
{
    __shared__ double sm[256];
    double s = 0.0;
    for (int i = threadIdx.x; i < n; i += 256) s += (double)partials[i];
    sm[threadIdx.x] = s;
    __syncthreads();
    for (int off = 128; off > 0; off >>= 1) {
        if (threadIdx.x < off) sm[threadIdx.x] += sm[threadIdx.x + off];
        __syncthreads();
    }
    if (threadIdx.x == 0) out[0] = (float)sm[0];
}

extern "C" void kernel_launch(void* const* d_in, const int* in_sizes, int n_in,
                              void* d_out, int out_size, void* d_ws, size_t ws_size,
                              hipStream_t stream) {
    const float* x = (const float*)d_in[0];   // output
    const float* y = (const float*)d_in[1];   // target
    float* partials = (float*)d_ws;           // NBLK floats (8 KB)
    combined_loss_kernel<<<NBLK, 256, 0, stream>>>(x, y, partials);
    reduce_kernel<<<1, 256, 0, stream>>>(partials, NBLK, (float*)d_out);
}